// Round 1
// baseline (702.030 us; speedup 1.0000x reference)
//
#include <hip/hip_runtime.h>
#include <hip/hip_cooperative_groups.h>
#include <stdint.h>

namespace cg = cooperative_groups;

#define THRESH 1.5f
constexpr int NPIX  = 8 * 1024 * 1024;   // 2^23 pixels
constexpr int HW    = 1024 * 1024;       // pixels per image
constexpr int WW    = 1024;              // image width
constexpr int NWORD = NPIX / 32;         // 262144 mask words
constexpr int WPR   = WW / 32;           // 32 words per image row

constexpr int BLK   = 256;
constexpr int GRID  = 1024;              // cooperative: exactly 4 blocks/CU on 256 CUs
constexpr int REGIONS  = NPIX / (BLK * 4);   // 8192 phase-1/5 regions (1024 px each)
constexpr int P1_ITERS = REGIONS / GRID;     // 8
static_assert(GRID * BLK == NWORD, "phase 2/3 assume exactly 1 word per thread");

// compact claim slots (unchanged geometry: claim region == 256 words == 8192 px)
constexpr int SPB        = 640;
constexpr int BASE_SLOTS = GRID * SPB;       // 655360
constexpr int OVF_SLOTS  = 16384;
constexpr int CAP        = BASE_SLOTS + OVF_SLOTS;

constexpr int WLSTRIDE = 1024;               // worklist entries per region

// ---------------------------------------------------------------------------
// parent[] encoding: < NPIX = union-find pointer (self <=> unclaimed root);
//                   >= NPIX = claimed root, compact id = value - NPIX.
// ---------------------------------------------------------------------------
__device__ __forceinline__ int find_root(const int* __restrict__ P, int x) {
    int p = P[x];
    while (p != x && p < NPIX) { x = p; p = P[x]; }
    return x;
}

__device__ __forceinline__ void merge(int* P, int a, int b) {
    int ra = find_root(P, a);
    int rb = find_root(P, b);
    while (ra != rb) {
        if (ra < rb) { int t = ra; ra = rb; rb = t; }   // ra > rb
        int old = atomicCAS(&P[ra], ra, rb);            // link larger -> smaller
        if (old == ra) break;
        ra = find_root(P, old);
        rb = find_root(P, rb);
    }
}

__device__ __forceinline__ int compact_id(const int* __restrict__ P, int p) {
    int e = P[p];                // direct root ptr or own claim
    if (e < NPIX) e = P[e];      // root's claim (>= NPIX after claim phase)
    return e - NPIX;
}

__device__ __forceinline__ void lookup_one(const int* __restrict__ parent,
                                           const int* __restrict__ cnt,
                                           const unsigned long long* __restrict__ best,
                                           int p, float& om, float& orow, float& ocol) {
    int cid = compact_id(parent, p);
    if (cid >= 0 && cid < CAP && cnt[cid] > 3) {       // area > MIN_AREA
        unsigned long long pk = best[cid];
        om   = __uint_as_float((unsigned)(pk >> 32));
        unsigned idx = ~((unsigned)pk);                // within-image flat idx
        orow = (float)(idx >> 10);
        ocol = (float)(idx & (WW - 1));
    }
}

// ---------------------------------------------------------------------------
// Single persistent cooperative kernel: 5 phases separated by grid.sync().
// Phase logic is identical to the previous 5-kernel pipeline; only the
// block->work mapping is grid-strided.
// ---------------------------------------------------------------------------
__global__ __launch_bounds__(BLK, 4) void fused_k(
    const float* __restrict__ x, float* __restrict__ o,
    int* __restrict__ parent, unsigned* __restrict__ mask,
    uint2* __restrict__ wl, int* __restrict__ wl_cnt,
    int* __restrict__ cnt, unsigned long long* __restrict__ best,
    int* __restrict__ ovf)
{
    cg::grid_group grid = cg::this_grid();
    __shared__ unsigned s_nib[BLK];
    __shared__ int s_rank;
    __shared__ int s_cnt;
    const int t = threadIdx.x;

    if (blockIdx.x == 0 && t == 0) *ovf = 0;

    // ---- Phase 1: read x once, build fg bitmask, init parent, append
    //      (pixel, value_bits) per fg pixel into per-region worklist. ----
    for (int it = 0; it < P1_ITERS; ++it) {
        int v  = (int)blockIdx.x + it * GRID;      // virtual region id
        int gt = v * BLK + t;
        int i4 = gt * 4;
        float4 vx = *(const float4*)(x + i4);
        unsigned nib = (unsigned)(vx.x >= THRESH) | ((unsigned)(vx.y >= THRESH) << 1) |
                       ((unsigned)(vx.z >= THRESH) << 2) | ((unsigned)(vx.w >= THRESH) << 3);
        *(int4*)(parent + i4) = make_int4(i4, i4 + 1, i4 + 2, i4 + 3);
        if (t == 0) s_rank = 0;
        s_nib[t] = nib;
        __syncthreads();
        if ((t & 7) == 0) {
            unsigned w = 0;
            #pragma unroll
            for (int k = 0; k < 8; k++) w |= s_nib[t + k] << (4 * k);
            mask[gt >> 3] = w;
        }
        int nfg = __popc(nib);
        if (nfg) {
            int r = atomicAdd(&s_rank, nfg);       // LDS atomic
            uint2* dst = wl + (size_t)v * WLSTRIDE;
            if (nib & 1u) dst[r++] = make_uint2((unsigned)i4,     __float_as_uint(vx.x));
            if (nib & 2u) dst[r++] = make_uint2((unsigned)i4 + 1, __float_as_uint(vx.y));
            if (nib & 4u) dst[r++] = make_uint2((unsigned)i4 + 2, __float_as_uint(vx.z));
            if (nib & 8u) dst[r++] = make_uint2((unsigned)i4 + 3, __float_as_uint(vx.w));
        }
        __syncthreads();
        if (t == 0) wl_cnt[v] = s_rank;
    }
    grid.sync();

    // ---- Phase 2: per-word union (32 px/thread); neighbor tests are bit-ops,
    //      only true 8-adjacency edges touch parent. ----
    {
        int w = blockIdx.x * BLK + t;              // exactly NWORD threads
        unsigned cur = mask[w];
        if (cur) {
            int r  = (w >> 5) & (WW - 1);          // row within image
            int cw = w & (WPR - 1);                // word-column within row
            unsigned prev = (cw > 0) ? mask[w - 1] : 0u;
            unsigned above = 0u, abovePrev = 0u, aboveNext = 0u;
            if (r > 0) {
                above     = mask[w - WPR];
                abovePrev = (cw > 0)       ? mask[w - WPR - 1] : 0u;
                aboveNext = (cw < WPR - 1) ? mask[w - WPR + 1] : 0u;
            }
            int base = w << 5;
            unsigned mW  = cur & ((cur   << 1) | (prev      >> 31));
            unsigned mN  = cur & above;
            unsigned mNW = cur & ((above << 1) | (abovePrev >> 31));
            unsigned mNE = cur & ((above >> 1) | ((aboveNext & 1u) << 31));
            while (mW)  { int b = __ffs(mW)  - 1; mW  &= mW  - 1; merge(parent, base + b, base + b - 1); }
            while (mN)  { int b = __ffs(mN)  - 1; mN  &= mN  - 1; merge(parent, base + b, base + b - WW); }
            while (mNW) { int b = __ffs(mNW) - 1; mNW &= mNW - 1; merge(parent, base + b, base + b - WW - 1); }
            while (mNE) { int b = __ffs(mNE) - 1; mNE &= mNE - 1; merge(parent, base + b, base + b - WW + 1); }
        }
    }
    grid.sync();

    // ---- Phase 3: per-word compress every fg pixel + deterministic per-block
    //      slot claim; claimer zero-inits its slot's cnt/best. ----
    {
        if (t == 0) s_cnt = 0;
        __syncthreads();
        int w = blockIdx.x * BLK + t;
        unsigned cur = mask[w];
        int base = w << 5;
        while (cur) {
            int b = __ffs(cur) - 1; cur &= cur - 1;
            int p = base + b;
            int root = find_root(parent, p);
            if (root == p) {
                int rank = atomicAdd(&s_cnt, 1);   // LDS atomic
                int slot;
                if (rank < SPB) slot = blockIdx.x * SPB + rank;
                else { int ofo = atomicAdd(ovf, 1); slot = BASE_SLOTS + (ofo < OVF_SLOTS ? ofo : OVF_SLOTS - 1); }
                cnt[slot] = 0; best[slot] = 0ull;
                parent[p] = NPIX + slot;
            } else {
                parent[p] = root;                  // full path compression
            }
        }
    }
    grid.sync();

    // ---- Phase 4: stats over the worklist — one wave per region (2 regions
    //      per wave), fully-active lanes, coalesced 8B reads. ----
    {
        int gw   = (int)blockIdx.x * (BLK / 64) + (t >> 6);   // 4096 waves
        int lane = t & 63;
        for (int r = gw; r < REGIONS; r += GRID * (BLK / 64)) {
            int c = wl_cnt[r];
            const uint2* src = wl + (size_t)r * WLSTRIDE;
            for (int j = lane; j < c; j += 64) {
                uint2 e = src[j];
                int p = (int)e.x;
                int cid = compact_id(parent, p);
                if (cid < 0 || cid >= CAP) continue;
                atomicAdd(&cnt[cid], 1);
                unsigned within = (unsigned)(p & (HW - 1));
                unsigned long long pk =
                    ((unsigned long long)e.y << 32) | (unsigned long long)(~within);
                atomicMax(&best[cid], pk);
            }
        }
    }
    grid.sync();

    // ---- Phase 5: emit float32 planes (max,row,col) with float4 stores. ----
    for (int it = 0; it < P1_ITERS; ++it) {
        int tt = ((int)blockIdx.x + it * GRID) * BLK + t;
        unsigned nib = (mask[tt >> 3] >> ((tt & 7) * 4)) & 0xFu;
        int i4 = tt * 4;
        float4 m  = make_float4(0.f, 0.f, 0.f, 0.f);
        float4 rr = make_float4(-1.f, -1.f, -1.f, -1.f);
        float4 cc = make_float4(-1.f, -1.f, -1.f, -1.f);
        if (nib) {
            if (nib & 1u) lookup_one(parent, cnt, best, i4,     m.x, rr.x, cc.x);
            if (nib & 2u) lookup_one(parent, cnt, best, i4 + 1, m.y, rr.y, cc.y);
            if (nib & 4u) lookup_one(parent, cnt, best, i4 + 2, m.z, rr.z, cc.z);
            if (nib & 8u) lookup_one(parent, cnt, best, i4 + 3, m.w, rr.w, cc.w);
        }
        *(float4*)(o + i4)            = m;
        *(float4*)(o + NPIX + i4)     = rr;
        *(float4*)(o + 2 * NPIX + i4) = cc;
    }
}

// ---------------------------------------------------------------------------
extern "C" void kernel_launch(void* const* d_in, const int* in_sizes, int n_in,
                              void* d_out, int out_size, void* d_ws, size_t ws_size,
                              hipStream_t stream) {
    const float* x = (const float*)d_in[0];
    float* o = (float*)d_out;

    // ws layout: parent i32[NPIX] 33.5MB | best u64[CAP] 5.4MB | cnt i32[CAP]
    // 2.7MB | mask u32[NWORD] 1MB | wl_cnt i32[8192] | wl uint2[8192*1024]
    // 67MB | ovf. Total ~110MB.
    char* base = (char*)d_ws;
    int* parent = (int*)base;
    size_t off = (size_t)NPIX * 4;
    unsigned long long* best = (unsigned long long*)(base + off);  off += (size_t)CAP * 8;
    int* cnt       = (int*)(base + off);                           off += (size_t)CAP * 4;
    unsigned* mask = (unsigned*)(base + off);                      off += (size_t)NWORD * 4;
    int* wl_cnt    = (int*)(base + off);                           off += (size_t)REGIONS * 4;
    uint2* wl      = (uint2*)(base + off);                         off += (size_t)REGIONS * WLSTRIDE * 8;
    int* ovf       = (int*)(base + off);

    void* args[] = { (void*)&x, (void*)&o, (void*)&parent, (void*)&mask,
                     (void*)&wl, (void*)&wl_cnt, (void*)&cnt, (void*)&best,
                     (void*)&ovf };
    hipLaunchCooperativeKernel((const void*)fused_k, dim3(GRID), dim3(BLK),
                               args, 0, stream);
}

// Round 2
// 378.332 us; speedup vs baseline: 1.8556x; 1.8556x over previous
//
#include <hip/hip_runtime.h>
#include <stdint.h>

#define THRESH 1.5f
constexpr int NPIX  = 8 * 1024 * 1024;   // 2^23 pixels
constexpr int HW    = 1024 * 1024;       // pixels per image
constexpr int WW    = 1024;              // image width
constexpr int NWORD = NPIX / 32;         // 262144 mask words
constexpr int WPR   = WW / 32;           // 32 words per image row

constexpr int BLK     = 256;
constexpr int GRD_PX4 = NPIX / (BLK * 4);  // 8192 blocks (4 px/thread; 1024 px/block)
constexpr int GRD_W   = NWORD / BLK;       // 1024 blocks (1 word/thread)

// compact slot region: slots allocated by a single global counter during the
// fused claim+stats pass. Worst case one alloc per worklist entry (~560k for
// this input) — CAP 671744 covers it with margin; last slot is a sacrificial
// dump in the (statistically impossible) overflow case.
constexpr int CAP = 671744;
// cnt(i32)+best(u64) zero region = CAP*12 bytes, zeroed with int4 stores.
constexpr int ZINT4 = CAP * 12 / 16;       // 503808 (exact)
static_assert((CAP * 12) % 16 == 0, "zero region must be int4-divisible");

constexpr int WLSTRIDE = 1024;             // worklist entries per mask_init block

// ---------------------------------------------------------------------------
// parent[] encoding: < NPIX = union-find pointer (self <=> unclaimed root);
//                   >= NPIX = claimed root, compact id = value - NPIX.
// ---------------------------------------------------------------------------
__device__ __forceinline__ int find_root(const int* __restrict__ P, int x) {
    int p = P[x];
    while (p != x && p < NPIX) { x = p; p = P[x]; }
    return x;
}

__device__ __forceinline__ void merge(int* P, int a, int b) {
    int ra = find_root(P, a);
    int rb = find_root(P, b);
    while (ra != rb) {
        if (ra < rb) { int t = ra; ra = rb; rb = t; }   // ra > rb
        int old = atomicCAS(&P[ra], ra, rb);            // link larger -> smaller
        if (old == ra) break;
        ra = find_root(P, old);
        rb = find_root(P, rb);
    }
}

// Pass 1: read x once (float4), build fg bitmask, init parent, zero the
// cnt/best stats region, and append (pixel, value_bits) per fg pixel into
// this block's worklist region.
__global__ void mask_init_k(const float* __restrict__ x, int* __restrict__ parent,
                            unsigned* __restrict__ mask, uint2* __restrict__ wl,
                            int* __restrict__ wl_cnt, int4* __restrict__ zbase,
                            int* __restrict__ gcnt) {
    __shared__ unsigned s_nib[BLK];
    __shared__ int s_rank;
    int t  = threadIdx.x;
    int gt = blockIdx.x * BLK + t;
    // bulk-zero cnt/best (contiguous CAP*12 bytes); no claimer-init race later
    if (gt < ZINT4) zbase[gt] = make_int4(0, 0, 0, 0);
    int i4 = gt * 4;
    float4 v = *(const float4*)(x + i4);
    unsigned nib = (unsigned)(v.x >= THRESH) | ((unsigned)(v.y >= THRESH) << 1) |
                   ((unsigned)(v.z >= THRESH) << 2) | ((unsigned)(v.w >= THRESH) << 3);
    *(int4*)(parent + i4) = make_int4(i4, i4 + 1, i4 + 2, i4 + 3);
    if (t == 0) s_rank = 0;
    s_nib[t] = nib;
    __syncthreads();
    if ((t & 7) == 0) {
        unsigned w = 0;
        #pragma unroll
        for (int k = 0; k < 8; k++) w |= s_nib[t + k] << (4 * k);
        mask[gt >> 3] = w;
    }
    int nfg = __popc(nib);
    if (nfg) {
        int r = atomicAdd(&s_rank, nfg);                // LDS atomic
        uint2* dst = wl + (size_t)blockIdx.x * WLSTRIDE;
        if (nib & 1u) dst[r++] = make_uint2((unsigned)i4,     __float_as_uint(v.x));
        if (nib & 2u) dst[r++] = make_uint2((unsigned)i4 + 1, __float_as_uint(v.y));
        if (nib & 4u) dst[r++] = make_uint2((unsigned)i4 + 2, __float_as_uint(v.z));
        if (nib & 8u) dst[r++] = make_uint2((unsigned)i4 + 3, __float_as_uint(v.w));
    }
    __syncthreads();
    if (t == 0) wl_cnt[blockIdx.x] = s_rank;
    if (gt == 0) *gcnt = 0;
}

// Pass 2: per-WORD union (32 px/thread); neighbor tests are bit-ops on the
// mask, only true 8-adjacency edges (~150k) touch parent.
__global__ void union_k(const unsigned* __restrict__ mask, int* __restrict__ parent) {
    int w = blockIdx.x * BLK + threadIdx.x;
    unsigned cur = mask[w];
    if (!cur) return;
    int r  = (w >> 5) & (WW - 1);   // row within image (words never cross rows)
    int cw = w & (WPR - 1);         // word-column within row
    unsigned prev = (cw > 0) ? mask[w - 1] : 0u;
    unsigned above = 0u, abovePrev = 0u, aboveNext = 0u;
    if (r > 0) {
        above     = mask[w - WPR];
        abovePrev = (cw > 0)       ? mask[w - WPR - 1] : 0u;
        aboveNext = (cw < WPR - 1) ? mask[w - WPR + 1] : 0u;
    }
    int base = w << 5;
    unsigned mW  = cur & ((cur   << 1) | (prev      >> 31));
    unsigned mN  = cur & above;
    unsigned mNW = cur & ((above << 1) | (abovePrev >> 31));
    unsigned mNE = cur & ((above >> 1) | ((aboveNext & 1u) << 31));
    while (mW)  { int b = __ffs(mW)  - 1; mW  &= mW  - 1; merge(parent, base + b, base + b - 1); }
    while (mN)  { int b = __ffs(mN)  - 1; mN  &= mN  - 1; merge(parent, base + b, base + b - WW); }
    while (mNW) { int b = __ffs(mNW) - 1; mNW &= mNW - 1; merge(parent, base + b, base + b - WW - 1); }
    while (mNE) { int b = __ffs(mNE) - 1; mNE &= mNE - 1; merge(parent, base + b, base + b - WW + 1); }
}

// Lazy claim: walk to the terminal of p's chain. If it ends at an unclaimed
// self-root, allocate a slot and CAS the claim in; CAS losers adopt the
// winner's slot (the wasted alloc is bounded by worklist size < CAP).
// Post-union, parent[x] only ever changes root->claim, so the walk terminates
// even with stale (per-XCD L2) plain reads: the CAS is coherent and arbitrates.
__device__ __forceinline__ int claim_cid(int* __restrict__ P, int p,
                                         int* __restrict__ gcnt) {
    int x = p;
    while (true) {
        int e = P[x];
        if (e >= NPIX) return e - NPIX;          // claimed terminal
        if (e == x) {                            // unclaimed self-root: try claim
            int slot = atomicAdd(gcnt, 1);
            if (slot >= CAP) slot = CAP - 1;     // sacrificial dump slot
            int old = atomicCAS(&P[x], x, NPIX + slot);
            if (old == x)     return slot;       // we claimed it
            if (old >= NPIX)  return old - NPIX; // lost to another claimer
            x = old;                             // defensive (can't occur post-union)
        } else {
            x = e;
        }
    }
}

// Pass 3 (fused claim+stats): over the worklist — one wave per mask_init
// region, fully-active lanes, coalesced 8B reads. Claims roots on the fly,
// fully flattens parent[p] -> NPIX+cid (so out_k is a single read), and
// accumulates area + fused (max value, min index of max) via one 64-bit
// atomicMax on (float_bits << 32) | ~within_index.
__global__ void cstats_k(const uint2* __restrict__ wl, const int* __restrict__ wl_cnt,
                         int* __restrict__ parent, int* __restrict__ cnt,
                         unsigned long long* __restrict__ best,
                         int* __restrict__ gcnt) {
    int region = blockIdx.x;
    int c = wl_cnt[region];
    const uint2* src = wl + (size_t)region * WLSTRIDE;
    for (int j = threadIdx.x; j < c; j += 64) {
        uint2 e = src[j];
        int p = (int)e.x;
        int cid = claim_cid(parent, p, gcnt);
        if (cid < 0 || cid >= CAP) continue;
        parent[p] = NPIX + cid;                 // full flatten for out_k
        atomicAdd(&cnt[cid], 1);
        unsigned within = (unsigned)(p & (HW - 1));
        unsigned long long pk =
            ((unsigned long long)e.y << 32) | (unsigned long long)(~within);
        atomicMax(&best[cid], pk);
    }
}

// Pass 4: emit float32 planes (max,row,col) with float4 stores.
// parent[p] is fully flattened for every fg pixel: one read -> cid.
__device__ __forceinline__ void lookup_one(const int* __restrict__ parent,
                                           const int* __restrict__ cnt,
                                           const unsigned long long* __restrict__ best,
                                           int p, float& om, float& orow, float& ocol) {
    int cid = parent[p] - NPIX;
    if (cid >= 0 && cid < CAP && cnt[cid] > 3) {       // area > MIN_AREA
        unsigned long long pk = best[cid];
        om   = __uint_as_float((unsigned)(pk >> 32));
        unsigned idx = ~((unsigned)pk);                // within-image flat idx
        orow = (float)(idx >> 10);
        ocol = (float)(idx & (WW - 1));
    }
}

__global__ void out_k(const unsigned* __restrict__ mask, const int* __restrict__ parent,
                      const int* __restrict__ cnt,
                      const unsigned long long* __restrict__ best,
                      float* __restrict__ o) {
    int t = blockIdx.x * BLK + threadIdx.x;
    unsigned nib = (mask[t >> 3] >> ((t & 7) * 4)) & 0xFu;
    int i4 = t * 4;
    float4 m  = make_float4(0.f, 0.f, 0.f, 0.f);
    float4 rr = make_float4(-1.f, -1.f, -1.f, -1.f);
    float4 cc = make_float4(-1.f, -1.f, -1.f, -1.f);
    if (nib) {
        if (nib & 1u) lookup_one(parent, cnt, best, i4,     m.x, rr.x, cc.x);
        if (nib & 2u) lookup_one(parent, cnt, best, i4 + 1, m.y, rr.y, cc.y);
        if (nib & 4u) lookup_one(parent, cnt, best, i4 + 2, m.z, rr.z, cc.z);
        if (nib & 8u) lookup_one(parent, cnt, best, i4 + 3, m.w, rr.w, cc.w);
    }
    *(float4*)(o + i4)            = m;
    *(float4*)(o + NPIX + i4)     = rr;
    *(float4*)(o + 2 * NPIX + i4) = cc;
}

// ---------------------------------------------------------------------------
extern "C" void kernel_launch(void* const* d_in, const int* in_sizes, int n_in,
                              void* d_out, int out_size, void* d_ws, size_t ws_size,
                              hipStream_t stream) {
    const float* x = (const float*)d_in[0];
    float* o = (float*)d_out;

    // ws layout: parent i32[NPIX] 33.5MB | best u64[CAP] 5.4MB | cnt i32[CAP]
    // 2.7MB | mask u32[NWORD] 1MB | wl_cnt i32[8192] | wl uint2[8192*1024]
    // 67MB | gcnt. Total ~110MB.
    char* base = (char*)d_ws;
    int* parent = (int*)base;
    size_t off = (size_t)NPIX * 4;
    unsigned long long* best = (unsigned long long*)(base + off);
    int4* zbase = (int4*)(base + off);                             off += (size_t)CAP * 8;
    int* cnt       = (int*)(base + off);                           off += (size_t)CAP * 4;
    unsigned* mask = (unsigned*)(base + off);                      off += (size_t)NWORD * 4;
    int* wl_cnt    = (int*)(base + off);                           off += (size_t)GRD_PX4 * 4;
    uint2* wl      = (uint2*)(base + off);                         off += (size_t)GRD_PX4 * WLSTRIDE * 8;
    int* gcnt      = (int*)(base + off);

    mask_init_k<<<GRD_PX4, BLK, 0, stream>>>(x, parent, mask, wl, wl_cnt, zbase, gcnt);
    union_k    <<<GRD_W,   BLK, 0, stream>>>(mask, parent);
    cstats_k   <<<GRD_PX4, 64,  0, stream>>>(wl, wl_cnt, parent, cnt, best, gcnt);
    out_k      <<<GRD_PX4, BLK, 0, stream>>>(mask, parent, cnt, best, o);
}

// Round 3
// 196.269 us; speedup vs baseline: 3.5769x; 1.9276x over previous
//
#include <hip/hip_runtime.h>
#include <stdint.h>

#define THRESH 1.5f
constexpr int NPIX  = 8 * 1024 * 1024;   // 2^23 pixels
constexpr int HW    = 1024 * 1024;       // pixels per image
constexpr int WW    = 1024;              // image width
constexpr int NWORD = NPIX / 32;         // 262144 mask words
constexpr int WPR   = WW / 32;           // 32 words per image row

constexpr int BLK     = 256;
constexpr int GRD_PX4 = NPIX / (BLK * 4);  // 8192 blocks (4 px/thread; 1024 px/block)
constexpr int GRD_W   = NWORD / BLK;       // 1024 blocks (1 word/thread)

// Deterministic claim slots for the fused claim+stats pass: each of the 8192
// worklist-region blocks owns SPB_R slots, allocated by an LDS rank counter
// (round-2 post-mortem: a single global counter = ~420k serialized atomics
// = ~175us; per-block LDS ranks are the round-0-proven pattern).
// E[claims/region] ~ 51 (clusters intersecting 1024 px) + CAS-race waste;
// 128 ~ 11 sigma. Overflow falls back to a global counter (never in practice).
constexpr int SPB_R      = 128;
constexpr int BASE_SLOTS = GRD_PX4 * SPB_R;   // 1048576
constexpr int OVF_SLOTS  = 16384;
constexpr int CAP        = BASE_SLOTS + OVF_SLOTS;  // 1064960
// cnt(i32)+best(u64) zero region = CAP*12 bytes, zeroed with int4 stores.
constexpr int ZINT4 = CAP * 12 / 16;          // 798720 (exact)
static_assert((CAP * 12) % 16 == 0, "zero region must be int4-divisible");
static_assert(ZINT4 <= GRD_PX4 * BLK, "mask_init must cover the zero region");

constexpr int WLSTRIDE = 1024;             // worklist entries per mask_init block

// ---------------------------------------------------------------------------
// parent[] encoding: < NPIX = union-find pointer (self <=> unclaimed root);
//                   >= NPIX = claimed root, compact id = value - NPIX.
// ---------------------------------------------------------------------------
__device__ __forceinline__ int find_root(const int* __restrict__ P, int x) {
    int p = P[x];
    while (p != x && p < NPIX) { x = p; p = P[x]; }
    return x;
}

__device__ __forceinline__ void merge(int* P, int a, int b) {
    int ra = find_root(P, a);
    int rb = find_root(P, b);
    while (ra != rb) {
        if (ra < rb) { int t = ra; ra = rb; rb = t; }   // ra > rb
        int old = atomicCAS(&P[ra], ra, rb);            // link larger -> smaller
        if (old == ra) break;
        ra = find_root(P, old);
        rb = find_root(P, rb);
    }
}

// Pass 1: read x once (float4), build fg bitmask, init parent, bulk-zero the
// cnt/best stats region (contiguous, ~2us), and append (pixel, value_bits)
// per fg pixel into this block's worklist region.
__global__ void mask_init_k(const float* __restrict__ x, int* __restrict__ parent,
                            unsigned* __restrict__ mask, uint2* __restrict__ wl,
                            int* __restrict__ wl_cnt, int4* __restrict__ zbase,
                            int* __restrict__ ovf) {
    __shared__ unsigned s_nib[BLK];
    __shared__ int s_rank;
    int t  = threadIdx.x;
    int gt = blockIdx.x * BLK + t;
    if (gt < ZINT4) zbase[gt] = make_int4(0, 0, 0, 0);
    int i4 = gt * 4;
    float4 v = *(const float4*)(x + i4);
    unsigned nib = (unsigned)(v.x >= THRESH) | ((unsigned)(v.y >= THRESH) << 1) |
                   ((unsigned)(v.z >= THRESH) << 2) | ((unsigned)(v.w >= THRESH) << 3);
    *(int4*)(parent + i4) = make_int4(i4, i4 + 1, i4 + 2, i4 + 3);
    if (t == 0) s_rank = 0;
    s_nib[t] = nib;
    __syncthreads();
    if ((t & 7) == 0) {
        unsigned w = 0;
        #pragma unroll
        for (int k = 0; k < 8; k++) w |= s_nib[t + k] << (4 * k);
        mask[gt >> 3] = w;
    }
    int nfg = __popc(nib);
    if (nfg) {
        int r = atomicAdd(&s_rank, nfg);                // LDS atomic
        uint2* dst = wl + (size_t)blockIdx.x * WLSTRIDE;
        if (nib & 1u) dst[r++] = make_uint2((unsigned)i4,     __float_as_uint(v.x));
        if (nib & 2u) dst[r++] = make_uint2((unsigned)i4 + 1, __float_as_uint(v.y));
        if (nib & 4u) dst[r++] = make_uint2((unsigned)i4 + 2, __float_as_uint(v.z));
        if (nib & 8u) dst[r++] = make_uint2((unsigned)i4 + 3, __float_as_uint(v.w));
    }
    __syncthreads();
    if (t == 0) wl_cnt[blockIdx.x] = s_rank;
    if (gt == 0) *ovf = 0;
}

// Pass 2: per-WORD union (32 px/thread); neighbor tests are bit-ops on the
// mask, only true 8-adjacency edges (~150k) touch parent. (Known-good.)
__global__ void union_k(const unsigned* __restrict__ mask, int* __restrict__ parent) {
    int w = blockIdx.x * BLK + threadIdx.x;
    unsigned cur = mask[w];
    if (!cur) return;
    int r  = (w >> 5) & (WW - 1);   // row within image (words never cross rows)
    int cw = w & (WPR - 1);         // word-column within row
    unsigned prev = (cw > 0) ? mask[w - 1] : 0u;
    unsigned above = 0u, abovePrev = 0u, aboveNext = 0u;
    if (r > 0) {
        above     = mask[w - WPR];
        abovePrev = (cw > 0)       ? mask[w - WPR - 1] : 0u;
        aboveNext = (cw < WPR - 1) ? mask[w - WPR + 1] : 0u;
    }
    int base = w << 5;
    unsigned mW  = cur & ((cur   << 1) | (prev      >> 31));
    unsigned mN  = cur & above;
    unsigned mNW = cur & ((above << 1) | (abovePrev >> 31));
    unsigned mNE = cur & ((above >> 1) | ((aboveNext & 1u) << 31));
    while (mW)  { int b = __ffs(mW)  - 1; mW  &= mW  - 1; merge(parent, base + b, base + b - 1); }
    while (mN)  { int b = __ffs(mN)  - 1; mN  &= mN  - 1; merge(parent, base + b, base + b - WW); }
    while (mNW) { int b = __ffs(mNW) - 1; mNW &= mNW - 1; merge(parent, base + b, base + b - WW - 1); }
    while (mNE) { int b = __ffs(mNE) - 1; mNE &= mNE - 1; merge(parent, base + b, base + b - WW + 1); }
}

// Pass 3 (fused claim+stats): over the worklist — one wave per mask_init
// region, fully-active lanes, coalesced 8B reads. Claims roots on the fly
// with DETERMINISTIC per-block slots (LDS rank + region*SPB_R base; global
// ovf only as fallback), fully flattens parent[p] -> NPIX+cid so out_k is a
// single read, and accumulates area + fused (max value, min index of max)
// via one 64-bit atomicMax on (float_bits << 32) | ~within_index.
// Claim-walk termination: after union_k, parent[] only ever changes
// root -> claim (monotone); stale per-XCD reads are arbitrated by the CAS.
__global__ void cstats_k(const uint2* __restrict__ wl, const int* __restrict__ wl_cnt,
                         int* __restrict__ parent, int* __restrict__ cnt,
                         unsigned long long* __restrict__ best,
                         int* __restrict__ ovf) {
    __shared__ int s_cnt;
    if (threadIdx.x == 0) s_cnt = 0;
    __syncthreads();
    int region = blockIdx.x;
    int c = wl_cnt[region];
    const uint2* src = wl + (size_t)region * WLSTRIDE;
    for (int j = threadIdx.x; j < c; j += 64) {
        uint2 e = src[j];
        int p = (int)e.x;
        int cid;
        int xn = p;
        while (true) {
            int pe = parent[xn];
            if (pe >= NPIX) { cid = pe - NPIX; break; }      // claimed terminal
            if (pe == xn) {                                  // unclaimed self-root
                int rank = atomicAdd(&s_cnt, 1);             // LDS atomic
                int slot;
                if (rank < SPB_R) slot = region * SPB_R + rank;
                else { int o2 = atomicAdd(ovf, 1);
                       slot = BASE_SLOTS + (o2 < OVF_SLOTS ? o2 : OVF_SLOTS - 1); }
                int old = atomicCAS(&parent[xn], xn, NPIX + slot);
                if (old == xn)    { cid = slot; break; }     // we claimed it
                if (old >= NPIX)  { cid = old - NPIX; break; } // lost the race
                xn = old;                                    // defensive
            } else {
                xn = pe;
            }
        }
        parent[p] = NPIX + cid;                 // full flatten for out_k
        atomicAdd(&cnt[cid], 1);
        unsigned within = (unsigned)(p & (HW - 1));
        unsigned long long pk =
            ((unsigned long long)e.y << 32) | (unsigned long long)(~within);
        atomicMax(&best[cid], pk);
    }
}

// Pass 4: emit float32 planes (max,row,col) with float4 stores.
// parent[p] is fully flattened for every fg pixel: one read -> cid.
__device__ __forceinline__ void lookup_one(const int* __restrict__ parent,
                                           const int* __restrict__ cnt,
                                           const unsigned long long* __restrict__ best,
                                           int p, float& om, float& orow, float& ocol) {
    int cid = parent[p] - NPIX;
    if (cid >= 0 && cid < CAP && cnt[cid] > 3) {       // area > MIN_AREA
        unsigned long long pk = best[cid];
        om   = __uint_as_float((unsigned)(pk >> 32));
        unsigned idx = ~((unsigned)pk);                // within-image flat idx
        orow = (float)(idx >> 10);
        ocol = (float)(idx & (WW - 1));
    }
}

__global__ void out_k(const unsigned* __restrict__ mask, const int* __restrict__ parent,
                      const int* __restrict__ cnt,
                      const unsigned long long* __restrict__ best,
                      float* __restrict__ o) {
    int t = blockIdx.x * BLK + threadIdx.x;
    unsigned nib = (mask[t >> 3] >> ((t & 7) * 4)) & 0xFu;
    int i4 = t * 4;
    float4 m  = make_float4(0.f, 0.f, 0.f, 0.f);
    float4 rr = make_float4(-1.f, -1.f, -1.f, -1.f);
    float4 cc = make_float4(-1.f, -1.f, -1.f, -1.f);
    if (nib) {
        if (nib & 1u) lookup_one(parent, cnt, best, i4,     m.x, rr.x, cc.x);
        if (nib & 2u) lookup_one(parent, cnt, best, i4 + 1, m.y, rr.y, cc.y);
        if (nib & 4u) lookup_one(parent, cnt, best, i4 + 2, m.z, rr.z, cc.z);
        if (nib & 8u) lookup_one(parent, cnt, best, i4 + 3, m.w, rr.w, cc.w);
    }
    *(float4*)(o + i4)            = m;
    *(float4*)(o + NPIX + i4)     = rr;
    *(float4*)(o + 2 * NPIX + i4) = cc;
}

// ---------------------------------------------------------------------------
extern "C" void kernel_launch(void* const* d_in, const int* in_sizes, int n_in,
                              void* d_out, int out_size, void* d_ws, size_t ws_size,
                              hipStream_t stream) {
    const float* x = (const float*)d_in[0];
    float* o = (float*)d_out;

    // ws layout: parent i32[NPIX] 33.5MB | best u64[CAP] 8.5MB | cnt i32[CAP]
    // 4.3MB | mask u32[NWORD] 1MB | wl_cnt i32[8192] | wl uint2[8192*1024]
    // 67MB | ovf. Total ~115MB (< 384MB ws).
    char* base = (char*)d_ws;
    int* parent = (int*)base;
    size_t off = (size_t)NPIX * 4;
    unsigned long long* best = (unsigned long long*)(base + off);
    int4* zbase = (int4*)(base + off);                             off += (size_t)CAP * 8;
    int* cnt       = (int*)(base + off);                           off += (size_t)CAP * 4;
    unsigned* mask = (unsigned*)(base + off);                      off += (size_t)NWORD * 4;
    int* wl_cnt    = (int*)(base + off);                           off += (size_t)GRD_PX4 * 4;
    uint2* wl      = (uint2*)(base + off);                         off += (size_t)GRD_PX4 * WLSTRIDE * 8;
    int* ovf       = (int*)(base + off);

    mask_init_k<<<GRD_PX4, BLK, 0, stream>>>(x, parent, mask, wl, wl_cnt, zbase, ovf);
    union_k    <<<GRD_W,   BLK, 0, stream>>>(mask, parent);
    cstats_k   <<<GRD_PX4, 64,  0, stream>>>(wl, wl_cnt, parent, cnt, best, ovf);
    out_k      <<<GRD_PX4, BLK, 0, stream>>>(mask, parent, cnt, best, o);
}

// Round 4
// 189.730 us; speedup vs baseline: 3.7002x; 1.0345x over previous
//
#include <hip/hip_runtime.h>
#include <stdint.h>

#define THRESH 1.5f
constexpr int NPIX  = 8 * 1024 * 1024;   // 2^23 pixels
constexpr int HW    = 1024 * 1024;       // pixels per image
constexpr int WW    = 1024;              // image width
constexpr int NWORD = NPIX / 32;         // 262144 mask words
constexpr int WPR   = WW / 32;           // 32 words per image row

constexpr int BLK     = 256;
constexpr int GRD_PX4 = NPIX / (BLK * 4);  // 8192 blocks (1024 px = ONE image row each)
constexpr int GRD_W   = NWORD / BLK;       // 1024 blocks (1 word/thread)

// Deterministic claim slots (round-2 lesson: per-block LDS ranks, never a hot
// global counter). Region = one row; E[fg/row] ~ 68, sigma ~ 8; 128 ~ 7.5
// sigma above the mean; overflow falls back to a global counter (never hit).
constexpr int SPB_R      = 128;
constexpr int BASE_SLOTS = GRD_PX4 * SPB_R;   // 1048576
constexpr int OVF_SLOTS  = 16384;
constexpr int CAP        = BASE_SLOTS + OVF_SLOTS;  // 1064960
constexpr int ZINT4 = CAP * 12 / 16;          // cnt+best zero region in int4s
static_assert((CAP * 12) % 16 == 0, "zero region must be int4-divisible");
static_assert(ZINT4 <= GRD_PX4 * BLK, "mask_init must cover the zero region");

constexpr int WLSTRIDE = 1024;             // worklist entries per row region

// ---------------------------------------------------------------------------
// parent[] encoding: < NPIX = union-find pointer (self <=> unclaimed root);
//                   >= NPIX = claimed root, compact id = value - NPIX.
// Links always point larger -> smaller index (monotone; no cycles).
// ---------------------------------------------------------------------------

// Path-halving find (union phase only — no claims exist yet, all values
// < NPIX). The halving store is a benign race: it always writes an ancestor.
__device__ __forceinline__ int find_root(int* __restrict__ P, int x) {
    int p = P[x];
    while (p != x) {
        int g = P[p];
        if (g != p) P[x] = g;   // halve
        x = p; p = g;
    }
    return x;
}

__device__ __forceinline__ void merge(int* P, int a, int b) {
    int ra = find_root(P, a);
    int rb = find_root(P, b);
    while (ra != rb) {
        if (ra < rb) { int t = ra; ra = rb; rb = t; }   // ra > rb
        int old = atomicCAS(&P[ra], ra, rb);            // link larger -> smaller
        if (old == ra) break;
        ra = find_root(P, old);
        rb = find_root(P, rb);
    }
}

// Pass 1: one block per image row. Read x once (float4), build fg bitmask,
// bulk-zero cnt/best, append (pixel,value) worklist entries, and init parent
// with HORIZONTAL RUN STARTS (s_word holds the whole row, so every W-edge is
// resolved here for free; union_k then only handles N/NW/NE).
__global__ void mask_init_k(const float* __restrict__ x, int* __restrict__ parent,
                            unsigned* __restrict__ mask, uint2* __restrict__ wl,
                            int* __restrict__ wl_cnt, int4* __restrict__ zbase,
                            int* __restrict__ ovf) {
    __shared__ unsigned s_nib[BLK];
    __shared__ unsigned s_word[WPR];
    __shared__ int s_rank;
    int t  = threadIdx.x;
    int gt = blockIdx.x * BLK + t;
    if (gt < ZINT4) zbase[gt] = make_int4(0, 0, 0, 0);
    int i4 = gt * 4;
    float4 v = *(const float4*)(x + i4);
    unsigned nib = (unsigned)(v.x >= THRESH) | ((unsigned)(v.y >= THRESH) << 1) |
                   ((unsigned)(v.z >= THRESH) << 2) | ((unsigned)(v.w >= THRESH) << 3);
    if (t == 0) s_rank = 0;
    s_nib[t] = nib;
    __syncthreads();
    if ((t & 7) == 0) {
        unsigned w = 0;
        #pragma unroll
        for (int k = 0; k < 8; k++) w |= s_nib[t + k] << (4 * k);
        s_word[t >> 3] = w;
        mask[gt >> 3] = w;
    }
    __syncthreads();

    // horizontal run starts for this thread's 4 pixels (row-relative indices)
    int rowstart = blockIdx.x << 10;     // global pixel index of row start
    int r0 = t << 2;                     // row-relative index of pixel 0
    int rs0 = 0, rs1 = 0, rs2 = 0, rs3 = 0;
    if (nib & 1u) {
        bool prevSet = (r0 != 0) &&
            ((s_word[(r0 - 1) >> 5] >> ((r0 - 1) & 31)) & 1u);
        if (!prevSet) rs0 = r0;
        else {
            int wI = r0 >> 5, b = r0 & 31;
            unsigned notset = b ? (~s_word[wI] & ((1u << b) - 1)) : 0u;
            int j = wI;
            if (!notset) {
                j = wI - 1;
                while (j >= 0 && s_word[j] == 0xFFFFFFFFu) j--;
                notset = (j >= 0) ? ~s_word[j] : 0u;
            }
            rs0 = (j < 0) ? 0 : (j * 32 + (31 - __clz(notset)) + 1);
        }
    }
    if (nib & 2u) rs1 = (nib & 1u) ? rs0 : r0 + 1;
    if (nib & 4u) rs2 = (nib & 2u) ? rs1 : r0 + 2;
    if (nib & 8u) rs3 = (nib & 4u) ? rs2 : r0 + 3;
    int4 pv;
    pv.x = (nib & 1u) ? rowstart + rs0 : i4;
    pv.y = (nib & 2u) ? rowstart + rs1 : i4 + 1;
    pv.z = (nib & 4u) ? rowstart + rs2 : i4 + 2;
    pv.w = (nib & 8u) ? rowstart + rs3 : i4 + 3;
    *(int4*)(parent + i4) = pv;

    int nfg = __popc(nib);
    if (nfg) {
        int r = atomicAdd(&s_rank, nfg);                // LDS atomic
        uint2* dst = wl + (size_t)blockIdx.x * WLSTRIDE;
        if (nib & 1u) dst[r++] = make_uint2((unsigned)i4,     __float_as_uint(v.x));
        if (nib & 2u) dst[r++] = make_uint2((unsigned)i4 + 1, __float_as_uint(v.y));
        if (nib & 4u) dst[r++] = make_uint2((unsigned)i4 + 2, __float_as_uint(v.z));
        if (nib & 8u) dst[r++] = make_uint2((unsigned)i4 + 3, __float_as_uint(v.w));
    }
    __syncthreads();
    if (t == 0) wl_cnt[blockIdx.x] = s_rank;
    if (gt == 0) *ovf = 0;
}

// Pass 2: per-WORD union, N-family only (W-edges pre-resolved by run-start
// parents). Merge thinning (all bit-safe):
//   mNW &= ~mN : if pixel b also N-connects, above bits b-1,b are W-adjacent
//                (same above-run) -> diagonal merge redundant.
//   mNE &= ~mN : symmetric (above bits b,b+1 adjacent).
//   mN &= ~(mN<<1): consecutive N-contacts within one run/above-run pair
//                need only the first (both rows are W-connected runs).
__global__ void union_k(const unsigned* __restrict__ mask, int* __restrict__ parent) {
    int w = blockIdx.x * BLK + threadIdx.x;
    int r = (w >> 5) & (WW - 1);    // row within image (words never cross rows)
    if (r == 0) return;             // image top row: no north neighbors
    unsigned cur = mask[w];
    if (!cur) return;
    int cw = w & (WPR - 1);         // word-column within row
    unsigned above     = mask[w - WPR];
    unsigned abovePrev = (cw > 0)       ? mask[w - WPR - 1] : 0u;
    unsigned aboveNext = (cw < WPR - 1) ? mask[w - WPR + 1] : 0u;
    unsigned mN  = cur & above;
    unsigned mNW = cur & ((above << 1) | (abovePrev >> 31));
    unsigned mNE = cur & ((above >> 1) | ((aboveNext & 1u) << 31));
    mNW &= ~mN;
    mNE &= ~mN;
    mN  &= ~(mN << 1);
    if (!(mN | mNW | mNE)) return;
    int base = w << 5;
    while (mN)  { int b = __ffs(mN)  - 1; mN  &= mN  - 1; merge(parent, base + b, base + b - WW); }
    while (mNW) { int b = __ffs(mNW) - 1; mNW &= mNW - 1; merge(parent, base + b, base + b - WW - 1); }
    while (mNE) { int b = __ffs(mNE) - 1; mNE &= mNE - 1; merge(parent, base + b, base + b - WW + 1); }
}

// Pass 3 (fused claim+stats): one wave per row region over the worklist.
// Claims roots on the fly with deterministic per-block slots (LDS rank +
// region*SPB_R base), fully flattens parent[p] -> NPIX+cid (out_k invariant:
// every fg pixel is its own wl entry, flattened exactly once; values >= NPIX
// never decrease — hence NO path-halving stores in this walk), and
// accumulates area + fused (max value, min index of max) via one 64-bit
// atomicMax on (float_bits << 32) | ~within_index.
__global__ void cstats_k(const uint2* __restrict__ wl, const int* __restrict__ wl_cnt,
                         int* __restrict__ parent, int* __restrict__ cnt,
                         unsigned long long* __restrict__ best,
                         int* __restrict__ ovf) {
    __shared__ int s_cnt;
    if (threadIdx.x == 0) s_cnt = 0;
    __syncthreads();
    int region = blockIdx.x;
    int c = wl_cnt[region];
    const uint2* src = wl + (size_t)region * WLSTRIDE;
    for (int j = threadIdx.x; j < c; j += 64) {
        uint2 e = src[j];
        int p = (int)e.x;
        int cid;
        int xn = p;
        while (true) {
            int pe = parent[xn];
            if (pe >= NPIX) { cid = pe - NPIX; break; }      // claimed terminal
            if (pe == xn) {                                  // unclaimed self-root
                int rank = atomicAdd(&s_cnt, 1);             // LDS atomic
                int slot;
                if (rank < SPB_R) slot = region * SPB_R + rank;
                else { int o2 = atomicAdd(ovf, 1);
                       slot = BASE_SLOTS + (o2 < OVF_SLOTS ? o2 : OVF_SLOTS - 1); }
                int old = atomicCAS(&parent[xn], xn, NPIX + slot);
                if (old == xn)    { cid = slot; break; }     // we claimed it
                if (old >= NPIX)  { cid = old - NPIX; break; } // lost the race
                xn = old;                                    // defensive
            } else {
                xn = pe;
            }
        }
        parent[p] = NPIX + cid;                 // full flatten for out_k
        atomicAdd(&cnt[cid], 1);
        unsigned within = (unsigned)(p & (HW - 1));
        unsigned long long pk =
            ((unsigned long long)e.y << 32) | (unsigned long long)(~within);
        atomicMax(&best[cid], pk);
    }
}

// Pass 4: emit float32 planes (max,row,col) with float4 stores.
// parent[p] is fully flattened for every fg pixel: one read -> cid.
__device__ __forceinline__ void lookup_one(const int* __restrict__ parent,
                                           const int* __restrict__ cnt,
                                           const unsigned long long* __restrict__ best,
                                           int p, float& om, float& orow, float& ocol) {
    int cid = parent[p] - NPIX;
    if (cid >= 0 && cid < CAP && cnt[cid] > 3) {       // area > MIN_AREA
        unsigned long long pk = best[cid];
        om   = __uint_as_float((unsigned)(pk >> 32));
        unsigned idx = ~((unsigned)pk);                // within-image flat idx
        orow = (float)(idx >> 10);
        ocol = (float)(idx & (WW - 1));
    }
}

__global__ void out_k(const unsigned* __restrict__ mask, const int* __restrict__ parent,
                      const int* __restrict__ cnt,
                      const unsigned long long* __restrict__ best,
                      float* __restrict__ o) {
    int t = blockIdx.x * BLK + threadIdx.x;
    unsigned nib = (mask[t >> 3] >> ((t & 7) * 4)) & 0xFu;
    int i4 = t * 4;
    float4 m  = make_float4(0.f, 0.f, 0.f, 0.f);
    float4 rr = make_float4(-1.f, -1.f, -1.f, -1.f);
    float4 cc = make_float4(-1.f, -1.f, -1.f, -1.f);
    if (nib) {
        if (nib & 1u) lookup_one(parent, cnt, best, i4,     m.x, rr.x, cc.x);
        if (nib & 2u) lookup_one(parent, cnt, best, i4 + 1, m.y, rr.y, cc.y);
        if (nib & 4u) lookup_one(parent, cnt, best, i4 + 2, m.z, rr.z, cc.z);
        if (nib & 8u) lookup_one(parent, cnt, best, i4 + 3, m.w, rr.w, cc.w);
    }
    *(float4*)(o + i4)            = m;
    *(float4*)(o + NPIX + i4)     = rr;
    *(float4*)(o + 2 * NPIX + i4) = cc;
}

// ---------------------------------------------------------------------------
extern "C" void kernel_launch(void* const* d_in, const int* in_sizes, int n_in,
                              void* d_out, int out_size, void* d_ws, size_t ws_size,
                              hipStream_t stream) {
    const float* x = (const float*)d_in[0];
    float* o = (float*)d_out;

    // ws layout: parent i32[NPIX] 33.5MB | best u64[CAP] 8.5MB | cnt i32[CAP]
    // 4.3MB | mask u32[NWORD] 1MB | wl_cnt i32[8192] | wl uint2[8192*1024]
    // 67MB | ovf. Total ~115MB (< 384MB ws).
    char* base = (char*)d_ws;
    int* parent = (int*)base;
    size_t off = (size_t)NPIX * 4;
    unsigned long long* best = (unsigned long long*)(base + off);
    int4* zbase = (int4*)(base + off);                             off += (size_t)CAP * 8;
    int* cnt       = (int*)(base + off);                           off += (size_t)CAP * 4;
    unsigned* mask = (unsigned*)(base + off);                      off += (size_t)NWORD * 4;
    int* wl_cnt    = (int*)(base + off);                           off += (size_t)GRD_PX4 * 4;
    uint2* wl      = (uint2*)(base + off);                         off += (size_t)GRD_PX4 * WLSTRIDE * 8;
    int* ovf       = (int*)(base + off);

    mask_init_k<<<GRD_PX4, BLK, 0, stream>>>(x, parent, mask, wl, wl_cnt, zbase, ovf);
    union_k    <<<GRD_W,   BLK, 0, stream>>>(mask, parent);
    cstats_k   <<<GRD_PX4, 64,  0, stream>>>(wl, wl_cnt, parent, cnt, best, ovf);
    out_k      <<<GRD_PX4, BLK, 0, stream>>>(mask, parent, cnt, best, o);
}